// Round 3
// baseline (525.275 us; speedup 1.0000x reference)
//
#include <hip/hip_runtime.h>
#include <hip/hip_bf16.h>

// FRMIL: B=8, N=4096, D=1024, H=8 (dh=128), NC=2, image 64x64.
// Single-query attention: K/V GEMMs never materialized.
//  k_fused (512 thr, 512 blocks): per (b, 8x8 tile): phase A conv+logits+tile-softmax,
//  phase B conv-recompute + A-weighted sum. LDS stride 101 float4 (bank-conflict-free).

#define NTOK 4096
#define DD 1024

// ---------------- ws float offsets ----------------
#define FO_ARG 0         // 8 u64 = 16 floats
#define FO_S1  16        // 2048 u64 = 4096 floats
#define FO_CWT 4160      // 9216
#define FO_QP  13376     // 8192
#define FO_W   21568     // 65536
#define FO_C   87104     // 64   (cval)
#define FO_C2  87168     // 64   (scaled cls logit)
#define FO_MS  87232     // 64bh * 64tile * 2 = 8192
#define FO_YP  95424     // 64bh * 64tile * 1024 = 4194304
#define FO_Y   4289728   // 65536
#define FO_O1  4355264   // 8192
#define FO_O2  4363456   // 8192

#define LSTRIDE 101      // float4 stride per ch-group in staging LDS

__global__ void k_init(const float* __restrict__ convw, float* __restrict__ cwT) {
  int gid = blockIdx.x * 256 + threadIdx.x;
  if (gid < 9216) {
    int d = gid / 9, p = gid - d * 9;
    cwT[p * DD + d] = convw[gid];
  }
}

// ---------- argmax: stage 1 (no atomics), stage 2 ----------
__global__ void k_argmax1(const float* __restrict__ inp, const float* __restrict__ Wenc,
                          const float* __restrict__ benc, unsigned long long* __restrict__ s1buf) {
  __shared__ unsigned long long lb[4];
  int wave = threadIdx.x >> 6, lane = threadIdx.x & 63;
  int b = blockIdx.x >> 8;
  int r0 = ((blockIdx.x & 255) << 4) + (wave << 2);
  const float4* base = (const float4*)(inp + ((size_t)b * NTOK + r0) * DD);
  const float4* wp = (const float4*)Wenc;
  float s0 = 0.f, s1 = 0.f, s2 = 0.f, s3 = 0.f;
#pragma unroll
  for (int k = 0; k < 4; ++k) {
    int off = lane + (k << 6);
    float4 w4 = wp[off];
    float4 a0 = base[off];
    float4 a1 = base[256 + off];
    float4 a2 = base[512 + off];
    float4 a3 = base[768 + off];
    s0 = fmaf(w4.x, a0.x, s0); s0 = fmaf(w4.y, a0.y, s0); s0 = fmaf(w4.z, a0.z, s0); s0 = fmaf(w4.w, a0.w, s0);
    s1 = fmaf(w4.x, a1.x, s1); s1 = fmaf(w4.y, a1.y, s1); s1 = fmaf(w4.z, a1.z, s1); s1 = fmaf(w4.w, a1.w, s1);
    s2 = fmaf(w4.x, a2.x, s2); s2 = fmaf(w4.y, a2.y, s2); s2 = fmaf(w4.z, a2.z, s2); s2 = fmaf(w4.w, a2.w, s2);
    s3 = fmaf(w4.x, a3.x, s3); s3 = fmaf(w4.y, a3.y, s3); s3 = fmaf(w4.z, a3.z, s3); s3 = fmaf(w4.w, a3.w, s3);
  }
#pragma unroll
  for (int mk = 32; mk >= 1; mk >>= 1) {
    s0 += __shfl_xor(s0, mk); s1 += __shfl_xor(s1, mk);
    s2 += __shfl_xor(s2, mk); s3 += __shfl_xor(s3, mk);
  }
  if (lane == 0) {
    float be = benc[0];
    float v[4] = {s0 + be, s1 + be, s2 + be, s3 + be};
    unsigned long long bst = 0ull;
#pragma unroll
    for (int i = 0; i < 4; ++i) {
      unsigned u = __float_as_uint(v[i]);
      u = (u & 0x80000000u) ? ~u : (u | 0x80000000u);
      unsigned long long p = ((unsigned long long)u << 32) |
                             (unsigned long long)(0xFFFFFFFFu - (unsigned)(r0 + i));
      bst = bst > p ? bst : p;
    }
    lb[wave] = bst;
  }
  __syncthreads();
  if (threadIdx.x == 0) {
    unsigned long long m = lb[0];
#pragma unroll
    for (int i = 1; i < 4; ++i) m = m > lb[i] ? m : lb[i];
    s1buf[blockIdx.x] = m;
  }
}

__global__ void k_argmax2(const unsigned long long* __restrict__ s1buf,
                          unsigned long long* __restrict__ argbest) {
  __shared__ unsigned long long red[256];
  int tid = threadIdx.x, b = blockIdx.x;
  red[tid] = s1buf[b * 256 + tid];
  __syncthreads();
  for (int s = 128; s > 0; s >>= 1) {
    if (tid < s) { unsigned long long o = red[tid + s]; if (o > red[tid]) red[tid] = o; }
    __syncthreads();
  }
  if (tid == 0) argbest[b] = red[0];
}

// ---------- merged Qp + w/c/cls-logit per (b,h) ----------
__global__ void k_qpwc(const float* __restrict__ inp, const float* __restrict__ Wq,
                       const float* __restrict__ bq, const float* __restrict__ Wk,
                       const float* __restrict__ bk, const float* __restrict__ cls,
                       const unsigned long long* __restrict__ argbest,
                       float* __restrict__ Qp, float* __restrict__ wbuf,
                       float* __restrict__ cbuf, float* __restrict__ cbuf2) {
  __shared__ float qin[DD];
  __shared__ float q[128];
  __shared__ float red[256];
  const int tid = threadIdx.x;
  const int b = blockIdx.x >> 3, h = blockIdx.x & 7;
  const unsigned idxq = 0xFFFFFFFFu - (unsigned)(argbest[b] & 0xFFFFFFFFull);
  // load Q row into LDS
  {
    const float4* qr = (const float4*)(inp + ((size_t)b * NTOK + idxq) * DD);
    ((float4*)qin)[tid] = qr[tid];
  }
  __syncthreads();
  // phase 1: Qp slice (128 rows of Wq), wave-per-row
  {
    int wave = tid >> 6, lane = tid & 63;
    const float4* qv4 = (const float4*)qin;
    for (int r = 0; r < 32; ++r) {
      int i = h * 128 + (r << 2) + wave;
      const float4* wr = (const float4*)(Wq + (size_t)i * DD);
      float s = 0.f;
#pragma unroll
      for (int k = 0; k < 4; ++k) {
        float4 a = wr[lane + (k << 6)], x = qv4[lane + (k << 6)];
        s = fmaf(a.x, x.x, s); s = fmaf(a.y, x.y, s);
        s = fmaf(a.z, x.z, s); s = fmaf(a.w, x.w, s);
      }
#pragma unroll
      for (int mk = 32; mk >= 1; mk >>= 1) s += __shfl_xor(s, mk);
      if (lane == 0) {
        float v = s + bq[i];
        q[i - h * 128] = v;
        Qp[b * DD + i] = v;
      }
    }
  }
  __syncthreads();
  // cc = q . bk_h  (parallel reduce)
  red[tid] = (tid < 128) ? q[tid] * bk[h * 128 + tid] : 0.f;
  __syncthreads();
  for (int s = 128; s > 0; s >>= 1) { if (tid < s) red[tid] += red[tid + s]; __syncthreads(); }
  float cc = red[0];
  if (tid == 0) cbuf[b * 8 + h] = cc;
  __syncthreads();
  // w row + cls logit
  const float* Wkh = Wk + (size_t)(h * 128) * DD;
  float p = 0.f;
#pragma unroll
  for (int jj = 0; jj < 4; ++jj) {
    int j = tid + (jj << 8);
    float s0 = 0.f, s1 = 0.f, s2 = 0.f, s3 = 0.f;
    for (int d = 0; d < 128; d += 4) {
      s0 = fmaf(q[d],     Wkh[(d)     * DD + j], s0);
      s1 = fmaf(q[d + 1], Wkh[(d + 1) * DD + j], s1);
      s2 = fmaf(q[d + 2], Wkh[(d + 2) * DD + j], s2);
      s3 = fmaf(q[d + 3], Wkh[(d + 3) * DD + j], s3);
    }
    float s = (s0 + s1) + (s2 + s3);
    wbuf[(size_t)(b * 8 + h) * DD + j] = s;
    p = fmaf(s, cls[j], p);
  }
  red[tid] = p; __syncthreads();
  for (int s = 128; s > 0; s >>= 1) { if (tid < s) red[tid] += red[tid + s]; __syncthreads(); }
  if (tid == 0) cbuf2[b * 8 + h] = (red[0] + cc) * 0.03125f;
}

// ---------- fused conv + logits + tile-softmax + y (512 threads) ----------
// grid 512 = b(8) x tile(64: 8x8 grid of 8x8-token tiles).
// LDS: sred4[32 grp][101] float4 staging (51.7 KB, stride 101 -> conflict-free),
//      reused as logit-reduce scratch; atile[8h][64tok] e-values.
__global__ __launch_bounds__(512, 4) void k_fused(
    const float* __restrict__ inp, const float* __restrict__ convb,
    const float* __restrict__ cwT, const float* __restrict__ wbuf,
    const float* __restrict__ cbuf, const unsigned long long* __restrict__ argbest,
    float2* __restrict__ msbuf, float* __restrict__ ypart) {
  __shared__ float4 sred4[32 * LSTRIDE];
  __shared__ float atile[512];
  const int tid = threadIdx.x, bx = blockIdx.x;
  const int b = bx >> 6, tile = bx & 63;
  const int R0 = (tile >> 3) << 3, C0 = (tile & 7) << 3;
  const unsigned idxq = 0xFFFFFFFFu - (unsigned)(argbest[b] & 0xFFFFFFFFull);
  const float* inpb = inp + (size_t)b * NTOK * DD;
  const float* qrow = inpb + (size_t)idxq * DD;
  // staging ids: 32 ch-float4 groups x 16 pos-slots
  const int gg = tid & 31, ts = tid >> 5;
  // phase A ids: jg(16 ch-subgroups) x rq(4 row-quads) x ca(8 cols)
  const int jg = tid >> 5, rq = (tid >> 3) & 3, ca = tid & 7;
  const int r0a = rq << 1;

  float acc[2][8];
#pragma unroll
  for (int i = 0; i < 2; ++i)
#pragma unroll
    for (int h = 0; h < 8; ++h) acc[i][h] = 0.f;

  // ================= phase A: logits =================
  for (int cidx = 0; cidx < 8; ++cidx) {
    const int jc = cidx << 7;
    __syncthreads();
    {  // stage 128 channels of the 10x10 halo (relu(x - q))
      const int js = jc + (gg << 2);
      float4 qv = *(const float4*)(qrow + js);
      for (int t = ts; t < 100; t += 16) {
        int tr = t / 10, tc = t - tr * 10;
        int gr = R0 - 1 + tr, gc = C0 - 1 + tc;
        float4 v = make_float4(0.f, 0.f, 0.f, 0.f);
        if (gr >= 0 && gr < 64 && gc >= 0 && gc < 64) {
          float4 rv = *(const float4*)(inpb + (size_t)((gr << 6) + gc) * DD + js);
          v.x = fmaxf(rv.x - qv.x, 0.f); v.y = fmaxf(rv.y - qv.y, 0.f);
          v.z = fmaxf(rv.z - qv.z, 0.f); v.w = fmaxf(rv.w - qv.w, 0.f);
        }
        sred4[gg * LSTRIDE + t] = v;
      }
    }
    __syncthreads();
#pragma unroll
    for (int sub = 0; sub < 2; ++sub) {
      const int g = (sub << 4) + jg;
      const int j4 = jc + (g << 2);
      float4 cwr[9];
#pragma unroll
      for (int p = 0; p < 9; ++p) cwr[p] = *(const float4*)(cwT + p * DD + j4);
      float4 cb4 = *(const float4*)(convb + j4);
      const float4* fb = sred4 + g * LSTRIDE;
      float4 x0 = cb4, x1 = cb4;
      {
        float4 rw[4][3];
#pragma unroll
        for (int rr = 0; rr < 4; ++rr)
#pragma unroll
          for (int dc = 0; dc < 3; ++dc)
            rw[rr][dc] = fb[(r0a + rr) * 10 + ca + dc];
#pragma unroll
        for (int dr = 0; dr < 3; ++dr)
#pragma unroll
          for (int dc = 0; dc < 3; ++dc) {
            float4 w = cwr[dr * 3 + dc];
            float4 f0 = rw[dr][dc], f1 = rw[dr + 1][dc];
            x0.x = fmaf(w.x, f0.x, x0.x); x0.y = fmaf(w.y, f0.y, x0.y);
            x0.z = fmaf(w.z, f0.z, x0.z); x0.w = fmaf(w.w, f0.w, x0.w);
            x1.x = fmaf(w.x, f1.x, x1.x); x1.y = fmaf(w.y, f1.y, x1.y);
            x1.z = fmaf(w.z, f1.z, x1.z); x1.w = fmaf(w.w, f1.w, x1.w);
          }
        x0.x += rw[1][1].x; x0.y += rw[1][1].y; x0.z += rw[1][1].z; x0.w += rw[1][1].w;
        x1.x += rw[2][1].x; x1.y += rw[2][1].y; x1.z += rw[2][1].z; x1.w += rw[2][1].w;
      }
#pragma unroll
      for (int h = 0; h < 8; ++h) {
        float4 whv = *(const float4*)(wbuf + (size_t)(b * 8 + h) * DD + j4);
        float a0 = acc[0][h], a1 = acc[1][h];
        a0 = fmaf(whv.x, x0.x, a0); a0 = fmaf(whv.y, x0.y, a0);
        a0 = fmaf(whv.z, x0.z, a0); a0 = fmaf(whv.w, x0.w, a0);
        a1 = fmaf(whv.x, x1.x, a1); a1 = fmaf(whv.y, x1.y, a1);
        a1 = fmaf(whv.z, x1.z, a1); a1 = fmaf(whv.w, x1.w, a1);
        acc[0][h] = a0; acc[1][h] = a1;
      }
    }
  }
  // ---- reduce logits over 16 ch-subgroups, tile-local softmax ----
  __syncthreads();
  float* red = (float*)sred4;
#pragma unroll
  for (int it = 0; it < 2; ++it)
#pragma unroll
    for (int h = 0; h < 8; ++h)
      red[jg * 512 + ((r0a + it) * 8 + ca) * 8 + h] = acc[it][h];
  __syncthreads();
  {
    int o = tid;
    float s = 0.f;
#pragma unroll
    for (int g = 0; g < 16; ++g) s += red[g * 512 + o];
    int h = o & 7, tok = o >> 3;
    atile[h * 64 + tok] = (s + cbuf[b * 8 + h]) * 0.03125f;
  }
  __syncthreads();
  if (tid < 256) {
    int hh = tid >> 5, sl = tid & 31;
    float l1 = atile[hh * 64 + sl], l2 = atile[hh * 64 + 32 + sl];
    float mx = fmaxf(l1, l2);
#pragma unroll
    for (int mk = 16; mk >= 1; mk >>= 1) mx = fmaxf(mx, __shfl_xor(mx, mk));
    float e1 = __expf(l1 - mx), e2 = __expf(l2 - mx);
    float Ssum = e1 + e2;
#pragma unroll
    for (int mk = 16; mk >= 1; mk >>= 1) Ssum += __shfl_xor(Ssum, mk);
    atile[hh * 64 + sl] = e1; atile[hh * 64 + 32 + sl] = e2;
    if (sl == 0) msbuf[(b * 8 + hh) * 64 + tile] = make_float2(mx, Ssum);
  }
  // ================= phase B: y_t =================
  // ids: gB(32 ch-float4) x rh(2 row-halves) x cB(8 cols)
  const int gB = tid >> 4, rh = (tid >> 3) & 1, cB = tid & 7;
  const int rbase = rh << 2;
  for (int cidx = 0; cidx < 8; ++cidx) {
    const int jc = cidx << 7;
    __syncthreads();
    {
      const int js = jc + (gg << 2);
      float4 qv = *(const float4*)(qrow + js);
      for (int t = ts; t < 100; t += 16) {
        int tr = t / 10, tc = t - tr * 10;
        int gr = R0 - 1 + tr, gc = C0 - 1 + tc;
        float4 v = make_float4(0.f, 0.f, 0.f, 0.f);
        if (gr >= 0 && gr < 64 && gc >= 0 && gc < 64) {
          float4 rv = *(const float4*)(inpb + (size_t)((gr << 6) + gc) * DD + js);
          v.x = fmaxf(rv.x - qv.x, 0.f); v.y = fmaxf(rv.y - qv.y, 0.f);
          v.z = fmaxf(rv.z - qv.z, 0.f); v.w = fmaxf(rv.w - qv.w, 0.f);
        }
        sred4[gg * LSTRIDE + t] = v;
      }
    }
    __syncthreads();
    const int j4 = jc + (gB << 2);
    float4 cwr[9];
#pragma unroll
    for (int p = 0; p < 9; ++p) cwr[p] = *(const float4*)(cwT + p * DD + j4);
    float4 cb4 = *(const float4*)(convb + j4);
    const float4* fb = sred4 + gB * LSTRIDE;
    float4 y4[8];
#pragma unroll
    for (int h = 0; h < 8; ++h) y4[h] = make_float4(0.f, 0.f, 0.f, 0.f);
    float4 w0[3], w1[3], w2[3];
#pragma unroll
    for (int dc = 0; dc < 3; ++dc) {
      w0[dc] = fb[rbase * 10 + cB + dc];
      w1[dc] = fb[(rbase + 1) * 10 + cB + dc];
    }
#pragma unroll
    for (int k = 0; k < 4; ++k) {
#pragma unroll
      for (int dc = 0; dc < 3; ++dc) w2[dc] = fb[(rbase + k + 2) * 10 + cB + dc];
      float4 x4 = cb4;
#pragma unroll
      for (int dc = 0; dc < 3; ++dc) {
        float4 wa = cwr[dc], wb = cwr[3 + dc], wc = cwr[6 + dc];
        x4.x = fmaf(wa.x, w0[dc].x, x4.x); x4.y = fmaf(wa.y, w0[dc].y, x4.y);
        x4.z = fmaf(wa.z, w0[dc].z, x4.z); x4.w = fmaf(wa.w, w0[dc].w, x4.w);
        x4.x = fmaf(wb.x, w1[dc].x, x4.x); x4.y = fmaf(wb.y, w1[dc].y, x4.y);
        x4.z = fmaf(wb.z, w1[dc].z, x4.z); x4.w = fmaf(wb.w, w1[dc].w, x4.w);
        x4.x = fmaf(wc.x, w2[dc].x, x4.x); x4.y = fmaf(wc.y, w2[dc].y, x4.y);
        x4.z = fmaf(wc.z, w2[dc].z, x4.z); x4.w = fmaf(wc.w, w2[dc].w, x4.w);
      }
      x4.x += w1[1].x; x4.y += w1[1].y; x4.z += w1[1].z; x4.w += w1[1].w;
      int tok = ((rbase + k) << 3) + cB;
#pragma unroll
      for (int h = 0; h < 8; ++h) {
        float a = atile[h * 64 + tok];
        y4[h].x = fmaf(a, x4.x, y4[h].x); y4[h].y = fmaf(a, x4.y, y4[h].y);
        y4[h].z = fmaf(a, x4.z, y4[h].z); y4[h].w = fmaf(a, x4.w, y4[h].w);
      }
#pragma unroll
      for (int dc = 0; dc < 3; ++dc) { w0[dc] = w1[dc]; w1[dc] = w2[dc]; }
    }
    // reduce over the 16 lanes sharing gB (rh x cB)
#pragma unroll
    for (int h = 0; h < 8; ++h)
#pragma unroll
      for (int mk = 8; mk >= 1; mk >>= 1) {
        y4[h].x += __shfl_xor(y4[h].x, mk);
        y4[h].y += __shfl_xor(y4[h].y, mk);
        y4[h].z += __shfl_xor(y4[h].z, mk);
        y4[h].w += __shfl_xor(y4[h].w, mk);
      }
    if ((tid & 15) == 0) {
#pragma unroll
      for (int h = 0; h < 8; ++h)
        *(float4*)(ypart + ((size_t)(b * 8 + h) * 64 + tile) * DD + j4) = y4[h];
    }
  }
}

// ---------- flash-combine (512 blocks: bh x 8 ch-splits) ----------
__global__ void k_comb(const float2* __restrict__ msbuf, const float* __restrict__ cbuf2,
                       const float* __restrict__ cls, const float* __restrict__ ypart,
                       float* __restrict__ ybuf) {
  __shared__ float wgt[64];
  __shared__ float wclss;
  __shared__ float4 sacc[256];
  int tid = threadIdx.x;
  int bh = blockIdx.x >> 3, cs = blockIdx.x & 7;
  if (tid < 64) {
    float2 ms = msbuf[bh * 64 + tid];
    float m = ms.x, S = ms.y;
    float M = m;
#pragma unroll
    for (int mk = 32; mk >= 1; mk >>= 1) M = fmaxf(M, __shfl_xor(M, mk));
    float l0 = cbuf2[bh];
    M = fmaxf(M, l0);
    float w = __expf(m - M);
    float z = S * w;
#pragma unroll
    for (int mk = 32; mk >= 1; mk >>= 1) z += __shfl_xor(z, mk);
    float ec = __expf(l0 - M);
    float Z = z + ec;
    wgt[tid] = w / Z;
    if (tid == 0) wclss = ec / Z;
  }
  __syncthreads();
  int ch4 = (cs << 5) + (tid & 31);
  int tg = tid >> 5;
  const float* yp = ypart + (size_t)bh * 64 * DD + (ch4 << 2);
  float4 acc = make_float4(0.f, 0.f, 0.f, 0.f);
#pragma unroll
  for (int tt = 0; tt < 8; ++tt) {
    int t = tg * 8 + tt;
    float w = wgt[t];
    float4 v = *(const float4*)(yp + (size_t)t * DD);
    acc.x = fmaf(w, v.x, acc.x); acc.y = fmaf(w, v.y, acc.y);
    acc.z = fmaf(w, v.z, acc.z); acc.w = fmaf(w, v.w, acc.w);
  }
  sacc[tg * 32 + (tid & 31)] = acc;
  __syncthreads();
  if (tid < 32) {
    int c4 = (cs << 5) + tid;
    float4 s = sacc[tid];
#pragma unroll
    for (int g = 1; g < 8; ++g) {
      float4 v = sacc[g * 32 + tid];
      s.x += v.x; s.y += v.y; s.z += v.z; s.w += v.w;
    }
    float wc = wclss;
    float4 cv = *(const float4*)(cls + (c4 << 2));
    s.x = fmaf(wc, cv.x, s.x); s.y = fmaf(wc, cv.y, s.y);
    s.z = fmaf(wc, cv.z, s.z); s.w = fmaf(wc, cv.w, s.w);
    *(float4*)(ybuf + (size_t)bh * DD + (c4 << 2)) = s;
  }
}

__global__ void k_o1(const float* __restrict__ Wv, const float* __restrict__ bv,
                     const float* __restrict__ Qp, const float* __restrict__ ybuf,
                     float* __restrict__ O1) {
  int wave = threadIdx.x >> 6, lane = threadIdx.x & 63;
  int b = blockIdx.x >> 8;
  int i = ((blockIdx.x & 255) << 2) + wave;
  int h = i >> 7;
  const float4* wr = (const float4*)(Wv + (size_t)i * DD);
  const float4* yr = (const float4*)(ybuf + (size_t)(b * 8 + h) * DD);
  float s = 0.f;
#pragma unroll
  for (int k = 0; k < 4; ++k) {
    float4 a = wr[lane + (k << 6)], x = yr[lane + (k << 6)];
    s = fmaf(a.x, x.x, s); s = fmaf(a.y, x.y, s);
    s = fmaf(a.z, x.z, s); s = fmaf(a.w, x.w, s);
  }
  for (int m = 32; m > 0; m >>= 1) s += __shfl_xor(s, m);
  if (lane == 0) O1[b * DD + i] = Qp[b * DD + i] + bv[i] + s;
}

__global__ void k_o2(const float* __restrict__ Wo, const float* __restrict__ bo,
                     const float* __restrict__ O1, float* __restrict__ O2) {
  int wave = threadIdx.x >> 6, lane = threadIdx.x & 63;
  int b = blockIdx.x >> 8;
  int i = ((blockIdx.x & 255) << 2) + wave;
  const float4* wr = (const float4*)(Wo + (size_t)i * DD);
  const float4* xr = (const float4*)(O1 + (size_t)b * DD);
  float s = 0.f;
#pragma unroll
  for (int k = 0; k < 4; ++k) {
    float4 a = wr[lane + (k << 6)], x = xr[lane + (k << 6)];
    s = fmaf(a.x, x.x, s); s = fmaf(a.y, x.y, s);
    s = fmaf(a.z, x.z, s); s = fmaf(a.w, x.w, s);
  }
  for (int m = 32; m > 0; m >>= 1) s += __shfl_xor(s, m);
  if (lane == 0) O2[b * DD + i] = O1[b * DD + i] + fmaxf(s + bo[i], 0.f);
}

__global__ void k_out(const float* __restrict__ Wfc, const float* __restrict__ bfc,
                      const float* __restrict__ O2, float* __restrict__ out) {
  int wave = threadIdx.x >> 6, lane = threadIdx.x & 63;
  for (int p = wave; p < 16; p += 4) {
    int b = p >> 1, cc = p & 1;
    const float4* o = (const float4*)(O2 + (size_t)b * DD);
    const float4* wr = (const float4*)(Wfc + (size_t)cc * DD);
    float s = 0.f;
#pragma unroll
    for (int k = 0; k < 4; ++k) {
      float4 a = o[lane + (k << 6)], x = wr[lane + (k << 6)];
      s = fmaf(a.x, x.x, s); s = fmaf(a.y, x.y, s);
      s = fmaf(a.z, x.z, s); s = fmaf(a.w, x.w, s);
    }
    for (int m = 32; m > 0; m >>= 1) s += __shfl_xor(s, m);
    if (lane == 0) out[p] = s + bfc[cc];
  }
}

extern "C" void kernel_launch(void* const* d_in, const int* in_sizes, int n_in,
                              void* d_out, int out_size, void* d_ws, size_t ws_size,
                              hipStream_t stream) {
  const float* inp   = (const float*)d_in[0];
  const float* Wenc  = (const float*)d_in[1];
  const float* benc  = (const float*)d_in[2];
  const float* cls   = (const float*)d_in[3];
  const float* convw = (const float*)d_in[4];
  const float* convb = (const float*)d_in[5];
  const float* Wq    = (const float*)d_in[6];
  const float* bq    = (const float*)d_in[7];
  const float* Wk    = (const float*)d_in[8];
  const float* bk    = (const float*)d_in[9];
  const float* Wv    = (const float*)d_in[10];
  const float* bv    = (const float*)d_in[11];
  const float* Wo    = (const float*)d_in[12];
  const float* bo    = (const float*)d_in[13];
  const float* Wfc   = (const float*)d_in[14];
  const float* bfc   = (const float*)d_in[15];
  float* out = (float*)d_out;
  float* W = (float*)d_ws;
  unsigned long long* argbest = (unsigned long long*)(W + FO_ARG);
  unsigned long long* s1buf   = (unsigned long long*)(W + FO_S1);
  float* cwT   = W + FO_CWT;
  float* Qp    = W + FO_QP;
  float* wbuf  = W + FO_W;
  float* cbuf  = W + FO_C;
  float* cbuf2 = W + FO_C2;
  float2* msbuf = (float2*)(W + FO_MS);
  float* ypart = W + FO_YP;
  float* ybuf  = W + FO_Y;
  float* O1    = W + FO_O1;
  float* O2    = W + FO_O2;

  hipLaunchKernelGGL(k_init,    dim3(36),   dim3(256), 0, stream, convw, cwT);
  hipLaunchKernelGGL(k_argmax1, dim3(2048), dim3(256), 0, stream, inp, Wenc, benc, s1buf);
  hipLaunchKernelGGL(k_argmax2, dim3(8),    dim3(256), 0, stream, s1buf, argbest);
  hipLaunchKernelGGL(k_qpwc,    dim3(64),   dim3(256), 0, stream, inp, Wq, bq, Wk, bk, cls, argbest, Qp, wbuf, cbuf, cbuf2);
  hipLaunchKernelGGL(k_fused,   dim3(512),  dim3(512), 0, stream, inp, convb, cwT, wbuf, cbuf, argbest, msbuf, ypart);
  hipLaunchKernelGGL(k_comb,    dim3(512),  dim3(256), 0, stream, msbuf, cbuf2, cls, ypart, ybuf);
  hipLaunchKernelGGL(k_o1,      dim3(2048), dim3(256), 0, stream, Wv, bv, Qp, ybuf, O1);
  hipLaunchKernelGGL(k_o2,      dim3(2048), dim3(256), 0, stream, Wo, bo, O1, O2);
  hipLaunchKernelGGL(k_out,     dim3(1),    dim3(256), 0, stream, Wfc, bfc, O2, out);
}

// Round 4
// 386.530 us; speedup vs baseline: 1.3589x; 1.3589x over previous
//
#include <hip/hip_runtime.h>
#include <hip/hip_bf16.h>

// FRMIL: B=8, N=4096, D=1024, H=8 (dh=128), NC=2, image 64x64.
// Single-query attention: K/V GEMMs never materialized.
// NOTE: qh·bk_h is constant across keys -> cancels in softmax -> dropped.
//  k_fused (512 thr, 512 blocks): per (b, 8x8 tile): phase A conv+logits+tile-softmax,
//  phase B conv-recompute + A-weighted sum. LDS stride 101 float4 (conflict-free).
//  k_w: Wk read exactly once, each element reused for 8 batches.

#define NTOK 4096
#define DD 1024

// ---------------- ws float offsets ----------------
#define FO_ARG 0         // 8 u64 = 16 floats
#define FO_S1  16        // 2048 u64 = 4096 floats
#define FO_CWT 4160      // 9216
#define FO_QP  13376     // 8192
#define FO_W   21568     // 65536
#define FO_MS  87232     // 64bh * 64tile * 2 = 8192
#define FO_YP  95424     // 64bh * 64tile * 1024 = 4194304
#define FO_Y   4289728   // 65536
#define FO_O1  4355264   // 8192
#define FO_O2  4363456   // 8192

#define LSTRIDE 101      // float4 stride per ch-group in staging LDS

__global__ void k_init(const float* __restrict__ convw, float* __restrict__ cwT) {
  int gid = blockIdx.x * 256 + threadIdx.x;
  if (gid < 9216) {
    int d = gid / 9, p = gid - d * 9;
    cwT[p * DD + d] = convw[gid];
  }
}

// ---------- argmax: stage 1 (no atomics), stage 2 ----------
__global__ void k_argmax1(const float* __restrict__ inp, const float* __restrict__ Wenc,
                          const float* __restrict__ benc, unsigned long long* __restrict__ s1buf) {
  __shared__ unsigned long long lb[4];
  int wave = threadIdx.x >> 6, lane = threadIdx.x & 63;
  int b = blockIdx.x >> 8;
  int r0 = ((blockIdx.x & 255) << 4) + (wave << 2);
  const float4* base = (const float4*)(inp + ((size_t)b * NTOK + r0) * DD);
  const float4* wp = (const float4*)Wenc;
  float s0 = 0.f, s1 = 0.f, s2 = 0.f, s3 = 0.f;
#pragma unroll
  for (int k = 0; k < 4; ++k) {
    int off = lane + (k << 6);
    float4 w4 = wp[off];
    float4 a0 = base[off];
    float4 a1 = base[256 + off];
    float4 a2 = base[512 + off];
    float4 a3 = base[768 + off];
    s0 = fmaf(w4.x, a0.x, s0); s0 = fmaf(w4.y, a0.y, s0); s0 = fmaf(w4.z, a0.z, s0); s0 = fmaf(w4.w, a0.w, s0);
    s1 = fmaf(w4.x, a1.x, s1); s1 = fmaf(w4.y, a1.y, s1); s1 = fmaf(w4.z, a1.z, s1); s1 = fmaf(w4.w, a1.w, s1);
    s2 = fmaf(w4.x, a2.x, s2); s2 = fmaf(w4.y, a2.y, s2); s2 = fmaf(w4.z, a2.z, s2); s2 = fmaf(w4.w, a2.w, s2);
    s3 = fmaf(w4.x, a3.x, s3); s3 = fmaf(w4.y, a3.y, s3); s3 = fmaf(w4.z, a3.z, s3); s3 = fmaf(w4.w, a3.w, s3);
  }
#pragma unroll
  for (int mk = 32; mk >= 1; mk >>= 1) {
    s0 += __shfl_xor(s0, mk); s1 += __shfl_xor(s1, mk);
    s2 += __shfl_xor(s2, mk); s3 += __shfl_xor(s3, mk);
  }
  if (lane == 0) {
    float be = benc[0];
    float v[4] = {s0 + be, s1 + be, s2 + be, s3 + be};
    unsigned long long bst = 0ull;
#pragma unroll
    for (int i = 0; i < 4; ++i) {
      unsigned u = __float_as_uint(v[i]);
      u = (u & 0x80000000u) ? ~u : (u | 0x80000000u);
      unsigned long long p = ((unsigned long long)u << 32) |
                             (unsigned long long)(0xFFFFFFFFu - (unsigned)(r0 + i));
      bst = bst > p ? bst : p;
    }
    lb[wave] = bst;
  }
  __syncthreads();
  if (threadIdx.x == 0) {
    unsigned long long m = lb[0];
#pragma unroll
    for (int i = 1; i < 4; ++i) m = m > lb[i] ? m : lb[i];
    s1buf[blockIdx.x] = m;
  }
}

__global__ void k_argmax2(const unsigned long long* __restrict__ s1buf,
                          unsigned long long* __restrict__ argbest) {
  __shared__ unsigned long long red[256];
  int tid = threadIdx.x, b = blockIdx.x;
  red[tid] = s1buf[b * 256 + tid];
  __syncthreads();
  for (int s = 128; s > 0; s >>= 1) {
    if (tid < s) { unsigned long long o = red[tid + s]; if (o > red[tid]) red[tid] = o; }
    __syncthreads();
  }
  if (tid == 0) argbest[b] = red[0];
}

__global__ void k_qp(const float* __restrict__ inp, const float* __restrict__ Wq,
                     const float* __restrict__ bq, const unsigned long long* __restrict__ argbest,
                     float* __restrict__ Qp) {
  int wave = threadIdx.x >> 6, lane = threadIdx.x & 63;
  int b = blockIdx.x >> 8;
  int i = ((blockIdx.x & 255) << 2) + wave;
  unsigned idx = 0xFFFFFFFFu - (unsigned)(argbest[b] & 0xFFFFFFFFull);
  const float4* qr = (const float4*)(inp + ((size_t)b * NTOK + idx) * DD);
  const float4* wr = (const float4*)(Wq + (size_t)i * DD);
  float s = 0.f;
#pragma unroll
  for (int k = 0; k < 4; ++k) {
    float4 a = wr[lane + (k << 6)], x = qr[lane + (k << 6)];
    s = fmaf(a.x, x.x, s); s = fmaf(a.y, x.y, s);
    s = fmaf(a.z, x.z, s); s = fmaf(a.w, x.w, s);
  }
  for (int m = 32; m > 0; m >>= 1) s += __shfl_xor(s, m);
  if (lane == 0) Qp[b * DD + i] = s + bq[i];
}

// ---------- w[b,h,:] = Wk_h^T · Qp_h : Wk read ONCE, reused across 8 batches ----------
// grid 256 = h(8) x jb(32 blocks of 32 cols); 256 threads = ig(8 i-groups) x jl(32)
__global__ void k_w(const float* __restrict__ Wk, const float* __restrict__ Qp,
                    float* __restrict__ wbuf) {
  __shared__ float qs[1024];   // [b][i] for this head
  __shared__ float sred[2048]; // [ig][b][jl]
  const int tid = threadIdx.x;
  const int h = blockIdx.x >> 5, jb = blockIdx.x & 31;
  {
    int b = tid >> 5, i4 = tid & 31;
    ((float4*)qs)[b * 32 + i4] = ((const float4*)Qp)[b * 256 + (h << 5) + i4];
  }
  __syncthreads();
  const int jl = tid & 31, ig = tid >> 5;
  const float* wkp = Wk + (size_t)((h << 7) + (ig << 4)) * DD + (jb << 5) + jl;
  float acc[8];
#pragma unroll
  for (int b = 0; b < 8; ++b) acc[b] = 0.f;
#pragma unroll
  for (int ii = 0; ii < 16; ++ii) {
    float wv = wkp[(size_t)ii * DD];
    int i = (ig << 4) + ii;
#pragma unroll
    for (int b = 0; b < 8; ++b) acc[b] = fmaf(qs[(b << 7) + i], wv, acc[b]);
  }
#pragma unroll
  for (int b = 0; b < 8; ++b) sred[ig * 256 + (b << 5) + jl] = acc[b];
  __syncthreads();
  {
    int b = tid >> 5, j2 = tid & 31;
    float s = 0.f;
#pragma unroll
    for (int g = 0; g < 8; ++g) s += sred[g * 256 + (b << 5) + j2];
    wbuf[(size_t)((b << 3) + h) * DD + (jb << 5) + j2] = s;
  }
}

// ---------- fused conv + logits + tile-softmax + y (512 threads) ----------
// grid 512 = b(8) x tile(64: 8x8 grid of 8x8-token tiles).
__global__ __launch_bounds__(512, 4) void k_fused(
    const float* __restrict__ inp, const float* __restrict__ convb,
    const float* __restrict__ cwT, const float* __restrict__ wbuf,
    const unsigned long long* __restrict__ argbest,
    float2* __restrict__ msbuf, float* __restrict__ ypart) {
  __shared__ float4 sred4[32 * LSTRIDE];
  __shared__ float atile[512];
  const int tid = threadIdx.x, bx = blockIdx.x;
  const int b = bx >> 6, tile = bx & 63;
  const int R0 = (tile >> 3) << 3, C0 = (tile & 7) << 3;
  const unsigned idxq = 0xFFFFFFFFu - (unsigned)(argbest[b] & 0xFFFFFFFFull);
  const float* inpb = inp + (size_t)b * NTOK * DD;
  const float* qrow = inpb + (size_t)idxq * DD;
  const int gg = tid & 31, ts = tid >> 5;
  const int jg = tid >> 5, rq = (tid >> 3) & 3, ca = tid & 7;
  const int r0a = rq << 1;

  float acc[2][8];
#pragma unroll
  for (int i = 0; i < 2; ++i)
#pragma unroll
    for (int h = 0; h < 8; ++h) acc[i][h] = 0.f;

  // ================= phase A: logits =================
  for (int cidx = 0; cidx < 8; ++cidx) {
    const int jc = cidx << 7;
    __syncthreads();
    {  // stage 128 channels of the 10x10 halo (relu(x - q))
      const int js = jc + (gg << 2);
      float4 qv = *(const float4*)(qrow + js);
      for (int t = ts; t < 100; t += 16) {
        int tr = t / 10, tc = t - tr * 10;
        int gr = R0 - 1 + tr, gc = C0 - 1 + tc;
        float4 v = make_float4(0.f, 0.f, 0.f, 0.f);
        if (gr >= 0 && gr < 64 && gc >= 0 && gc < 64) {
          float4 rv = *(const float4*)(inpb + (size_t)((gr << 6) + gc) * DD + js);
          v.x = fmaxf(rv.x - qv.x, 0.f); v.y = fmaxf(rv.y - qv.y, 0.f);
          v.z = fmaxf(rv.z - qv.z, 0.f); v.w = fmaxf(rv.w - qv.w, 0.f);
        }
        sred4[gg * LSTRIDE + t] = v;
      }
    }
    __syncthreads();
#pragma unroll
    for (int sub = 0; sub < 2; ++sub) {
      const int g = (sub << 4) + jg;
      const int j4 = jc + (g << 2);
      float4 cwr[9];
#pragma unroll
      for (int p = 0; p < 9; ++p) cwr[p] = *(const float4*)(cwT + p * DD + j4);
      float4 cb4 = *(const float4*)(convb + j4);
      const float4* fb = sred4 + g * LSTRIDE;
      float4 x0 = cb4, x1 = cb4;
      {
        float4 rw[4][3];
#pragma unroll
        for (int rr = 0; rr < 4; ++rr)
#pragma unroll
          for (int dc = 0; dc < 3; ++dc)
            rw[rr][dc] = fb[(r0a + rr) * 10 + ca + dc];
#pragma unroll
        for (int dr = 0; dr < 3; ++dr)
#pragma unroll
          for (int dc = 0; dc < 3; ++dc) {
            float4 w = cwr[dr * 3 + dc];
            float4 f0 = rw[dr][dc], f1 = rw[dr + 1][dc];
            x0.x = fmaf(w.x, f0.x, x0.x); x0.y = fmaf(w.y, f0.y, x0.y);
            x0.z = fmaf(w.z, f0.z, x0.z); x0.w = fmaf(w.w, f0.w, x0.w);
            x1.x = fmaf(w.x, f1.x, x1.x); x1.y = fmaf(w.y, f1.y, x1.y);
            x1.z = fmaf(w.z, f1.z, x1.z); x1.w = fmaf(w.w, f1.w, x1.w);
          }
        x0.x += rw[1][1].x; x0.y += rw[1][1].y; x0.z += rw[1][1].z; x0.w += rw[1][1].w;
        x1.x += rw[2][1].x; x1.y += rw[2][1].y; x1.z += rw[2][1].z; x1.w += rw[2][1].w;
      }
#pragma unroll
      for (int h = 0; h < 8; ++h) {
        float4 whv = *(const float4*)(wbuf + (size_t)(b * 8 + h) * DD + j4);
        float a0 = acc[0][h], a1 = acc[1][h];
        a0 = fmaf(whv.x, x0.x, a0); a0 = fmaf(whv.y, x0.y, a0);
        a0 = fmaf(whv.z, x0.z, a0); a0 = fmaf(whv.w, x0.w, a0);
        a1 = fmaf(whv.x, x1.x, a1); a1 = fmaf(whv.y, x1.y, a1);
        a1 = fmaf(whv.z, x1.z, a1); a1 = fmaf(whv.w, x1.w, a1);
        acc[0][h] = a0; acc[1][h] = a1;
      }
    }
  }
  // ---- reduce logits over 16 ch-subgroups, tile-local softmax ----
  __syncthreads();
  float* red = (float*)sred4;
#pragma unroll
  for (int it = 0; it < 2; ++it)
#pragma unroll
    for (int h = 0; h < 8; ++h)
      red[jg * 512 + ((r0a + it) * 8 + ca) * 8 + h] = acc[it][h];
  __syncthreads();
  {
    int o = tid;
    float s = 0.f;
#pragma unroll
    for (int g = 0; g < 16; ++g) s += red[g * 512 + o];
    int h = o & 7, tok = o >> 3;
    atile[h * 64 + tok] = s * 0.03125f;
  }
  __syncthreads();
  if (tid < 256) {
    int hh = tid >> 5, sl = tid & 31;
    float l1 = atile[hh * 64 + sl], l2 = atile[hh * 64 + 32 + sl];
    float mx = fmaxf(l1, l2);
#pragma unroll
    for (int mk = 16; mk >= 1; mk >>= 1) mx = fmaxf(mx, __shfl_xor(mx, mk));
    float e1 = __expf(l1 - mx), e2 = __expf(l2 - mx);
    float Ssum = e1 + e2;
#pragma unroll
    for (int mk = 16; mk >= 1; mk >>= 1) Ssum += __shfl_xor(Ssum, mk);
    atile[hh * 64 + sl] = e1; atile[hh * 64 + 32 + sl] = e2;
    if (sl == 0) msbuf[(b * 8 + hh) * 64 + tile] = make_float2(mx, Ssum);
  }
  // ================= phase B: y_t =================
  const int gB = tid >> 4, rh = (tid >> 3) & 1, cB = tid & 7;
  const int rbase = rh << 2;
  for (int cidx = 0; cidx < 8; ++cidx) {
    const int jc = cidx << 7;
    __syncthreads();
    {
      const int js = jc + (gg << 2);
      float4 qv = *(const float4*)(qrow + js);
      for (int t = ts; t < 100; t += 16) {
        int tr = t / 10, tc = t - tr * 10;
        int gr = R0 - 1 + tr, gc = C0 - 1 + tc;
        float4 v = make_float4(0.f, 0.f, 0.f, 0.f);
        if (gr >= 0 && gr < 64 && gc >= 0 && gc < 64) {
          float4 rv = *(const float4*)(inpb + (size_t)((gr << 6) + gc) * DD + js);
          v.x = fmaxf(rv.x - qv.x, 0.f); v.y = fmaxf(rv.y - qv.y, 0.f);
          v.z = fmaxf(rv.z - qv.z, 0.f); v.w = fmaxf(rv.w - qv.w, 0.f);
        }
        sred4[gg * LSTRIDE + t] = v;
      }
    }
    __syncthreads();
    const int j4 = jc + (gB << 2);
    float4 cwr[9];
#pragma unroll
    for (int p = 0; p < 9; ++p) cwr[p] = *(const float4*)(cwT + p * DD + j4);
    float4 cb4 = *(const float4*)(convb + j4);
    const float4* fb = sred4 + gB * LSTRIDE;
    float4 y4[8];
#pragma unroll
    for (int h = 0; h < 8; ++h) y4[h] = make_float4(0.f, 0.f, 0.f, 0.f);
    float4 w0[3], w1[3], w2[3];
#pragma unroll
    for (int dc = 0; dc < 3; ++dc) {
      w0[dc] = fb[rbase * 10 + cB + dc];
      w1[dc] = fb[(rbase + 1) * 10 + cB + dc];
    }
#pragma unroll
    for (int k = 0; k < 4; ++k) {
#pragma unroll
      for (int dc = 0; dc < 3; ++dc) w2[dc] = fb[(rbase + k + 2) * 10 + cB + dc];
      float4 x4 = cb4;
#pragma unroll
      for (int dc = 0; dc < 3; ++dc) {
        float4 wa = cwr[dc], wb = cwr[3 + dc], wc = cwr[6 + dc];
        x4.x = fmaf(wa.x, w0[dc].x, x4.x); x4.y = fmaf(wa.y, w0[dc].y, x4.y);
        x4.z = fmaf(wa.z, w0[dc].z, x4.z); x4.w = fmaf(wa.w, w0[dc].w, x4.w);
        x4.x = fmaf(wb.x, w1[dc].x, x4.x); x4.y = fmaf(wb.y, w1[dc].y, x4.y);
        x4.z = fmaf(wb.z, w1[dc].z, x4.z); x4.w = fmaf(wb.w, w1[dc].w, x4.w);
        x4.x = fmaf(wc.x, w2[dc].x, x4.x); x4.y = fmaf(wc.y, w2[dc].y, x4.y);
        x4.z = fmaf(wc.z, w2[dc].z, x4.z); x4.w = fmaf(wc.w, w2[dc].w, x4.w);
      }
      x4.x += w1[1].x; x4.y += w1[1].y; x4.z += w1[1].z; x4.w += w1[1].w;
      int tok = ((rbase + k) << 3) + cB;
#pragma unroll
      for (int h = 0; h < 8; ++h) {
        float a = atile[h * 64 + tok];
        y4[h].x = fmaf(a, x4.x, y4[h].x); y4[h].y = fmaf(a, x4.y, y4[h].y);
        y4[h].z = fmaf(a, x4.z, y4[h].z); y4[h].w = fmaf(a, x4.w, y4[h].w);
      }
#pragma unroll
      for (int dc = 0; dc < 3; ++dc) { w0[dc] = w1[dc]; w1[dc] = w2[dc]; }
    }
#pragma unroll
    for (int h = 0; h < 8; ++h)
#pragma unroll
      for (int mk = 8; mk >= 1; mk >>= 1) {
        y4[h].x += __shfl_xor(y4[h].x, mk);
        y4[h].y += __shfl_xor(y4[h].y, mk);
        y4[h].z += __shfl_xor(y4[h].z, mk);
        y4[h].w += __shfl_xor(y4[h].w, mk);
      }
    if ((tid & 15) == 0) {
#pragma unroll
      for (int h = 0; h < 8; ++h)
        *(float4*)(ypart + ((size_t)(b * 8 + h) * 64 + tile) * DD + j4) = y4[h];
    }
  }
}

// ---------- flash-combine (512 blocks: bh x 8 ch-splits); computes l0 inline ----------
__global__ void k_comb(const float2* __restrict__ msbuf, const float* __restrict__ wbuf,
                       const float* __restrict__ cls, const float* __restrict__ ypart,
                       float* __restrict__ ybuf) {
  __shared__ float redl[256];
  __shared__ float wgt[64];
  __shared__ float wclss;
  __shared__ float4 sacc[256];
  int tid = threadIdx.x;
  int bh = blockIdx.x >> 3, cs = blockIdx.x & 7;
  {  // l0 = (w . cls) * scale   (qh·bk_h dropped: softmax-invariant)
    float4 a = ((const float4*)(wbuf + (size_t)bh * DD))[tid];
    float4 c = ((const float4*)cls)[tid];
    redl[tid] = a.x * c.x + a.y * c.y + a.z * c.z + a.w * c.w;
  }
  __syncthreads();
  for (int s = 128; s > 0; s >>= 1) { if (tid < s) redl[tid] += redl[tid + s]; __syncthreads(); }
  float l0 = redl[0] * 0.03125f;
  if (tid < 64) {
    float2 ms = msbuf[bh * 64 + tid];
    float m = ms.x, S = ms.y;
    float M = m;
#pragma unroll
    for (int mk = 32; mk >= 1; mk >>= 1) M = fmaxf(M, __shfl_xor(M, mk));
    M = fmaxf(M, l0);
    float w = __expf(m - M);
    float z = S * w;
#pragma unroll
    for (int mk = 32; mk >= 1; mk >>= 1) z += __shfl_xor(z, mk);
    float ec = __expf(l0 - M);
    float Z = z + ec;
    wgt[tid] = w / Z;
    if (tid == 0) wclss = ec / Z;
  }
  __syncthreads();
  int ch4 = (cs << 5) + (tid & 31);
  int tg = tid >> 5;
  const float* yp = ypart + (size_t)bh * 64 * DD + (ch4 << 2);
  float4 acc = make_float4(0.f, 0.f, 0.f, 0.f);
#pragma unroll
  for (int tt = 0; tt < 8; ++tt) {
    int t = tg * 8 + tt;
    float w = wgt[t];
    float4 v = *(const float4*)(yp + (size_t)t * DD);
    acc.x = fmaf(w, v.x, acc.x); acc.y = fmaf(w, v.y, acc.y);
    acc.z = fmaf(w, v.z, acc.z); acc.w = fmaf(w, v.w, acc.w);
  }
  sacc[tg * 32 + (tid & 31)] = acc;
  __syncthreads();
  if (tid < 32) {
    int c4 = (cs << 5) + tid;
    float4 s = sacc[tid];
#pragma unroll
    for (int g = 1; g < 8; ++g) {
      float4 v = sacc[g * 32 + tid];
      s.x += v.x; s.y += v.y; s.z += v.z; s.w += v.w;
    }
    float wc = wclss;
    float4 cv = *(const float4*)(cls + (c4 << 2));
    s.x = fmaf(wc, cv.x, s.x); s.y = fmaf(wc, cv.y, s.y);
    s.z = fmaf(wc, cv.z, s.z); s.w = fmaf(wc, cv.w, s.w);
    *(float4*)(ybuf + (size_t)bh * DD + (c4 << 2)) = s;
  }
}

__global__ void k_o1(const float* __restrict__ Wv, const float* __restrict__ bv,
                     const float* __restrict__ Qp, const float* __restrict__ ybuf,
                     float* __restrict__ O1) {
  int wave = threadIdx.x >> 6, lane = threadIdx.x & 63;
  int b = blockIdx.x >> 8;
  int i = ((blockIdx.x & 255) << 2) + wave;
  int h = i >> 7;
  const float4* wr = (const float4*)(Wv + (size_t)i * DD);
  const float4* yr = (const float4*)(ybuf + (size_t)(b * 8 + h) * DD);
  float s = 0.f;
#pragma unroll
  for (int k = 0; k < 4; ++k) {
    float4 a = wr[lane + (k << 6)], x = yr[lane + (k << 6)];
    s = fmaf(a.x, x.x, s); s = fmaf(a.y, x.y, s);
    s = fmaf(a.z, x.z, s); s = fmaf(a.w, x.w, s);
  }
  for (int m = 32; m > 0; m >>= 1) s += __shfl_xor(s, m);
  if (lane == 0) O1[b * DD + i] = Qp[b * DD + i] + bv[i] + s;
}

__global__ void k_o2(const float* __restrict__ Wo, const float* __restrict__ bo,
                     const float* __restrict__ O1, float* __restrict__ O2) {
  int wave = threadIdx.x >> 6, lane = threadIdx.x & 63;
  int b = blockIdx.x >> 8;
  int i = ((blockIdx.x & 255) << 2) + wave;
  const float4* wr = (const float4*)(Wo + (size_t)i * DD);
  const float4* xr = (const float4*)(O1 + (size_t)b * DD);
  float s = 0.f;
#pragma unroll
  for (int k = 0; k < 4; ++k) {
    float4 a = wr[lane + (k << 6)], x = xr[lane + (k << 6)];
    s = fmaf(a.x, x.x, s); s = fmaf(a.y, x.y, s);
    s = fmaf(a.z, x.z, s); s = fmaf(a.w, x.w, s);
  }
  for (int m = 32; m > 0; m >>= 1) s += __shfl_xor(s, m);
  if (lane == 0) O2[b * DD + i] = O1[b * DD + i] + fmaxf(s + bo[i], 0.f);
}

__global__ void k_out(const float* __restrict__ Wfc, const float* __restrict__ bfc,
                      const float* __restrict__ O2, float* __restrict__ out) {
  int wave = threadIdx.x >> 6, lane = threadIdx.x & 63;
  for (int p = wave; p < 16; p += 4) {
    int b = p >> 1, cc = p & 1;
    const float4* o = (const float4*)(O2 + (size_t)b * DD);
    const float4* wr = (const float4*)(Wfc + (size_t)cc * DD);
    float s = 0.f;
#pragma unroll
    for (int k = 0; k < 4; ++k) {
      float4 a = o[lane + (k << 6)], x = wr[lane + (k << 6)];
      s = fmaf(a.x, x.x, s); s = fmaf(a.y, x.y, s);
      s = fmaf(a.z, x.z, s); s = fmaf(a.w, x.w, s);
    }
    for (int m = 32; m > 0; m >>= 1) s += __shfl_xor(s, m);
    if (lane == 0) out[p] = s + bfc[cc];
  }
}

extern "C" void kernel_launch(void* const* d_in, const int* in_sizes, int n_in,
                              void* d_out, int out_size, void* d_ws, size_t ws_size,
                              hipStream_t stream) {
  const float* inp   = (const float*)d_in[0];
  const float* Wenc  = (const float*)d_in[1];
  const float* benc  = (const float*)d_in[2];
  const float* cls   = (const float*)d_in[3];
  const float* convw = (const float*)d_in[4];
  const float* convb = (const float*)d_in[5];
  const float* Wq    = (const float*)d_in[6];
  const float* bq    = (const float*)d_in[7];
  const float* Wk    = (const float*)d_in[8];
  const float* bv    = (const float*)d_in[11];
  const float* Wv    = (const float*)d_in[10];
  const float* Wo    = (const float*)d_in[12];
  const float* bo    = (const float*)d_in[13];
  const float* Wfc   = (const float*)d_in[14];
  const float* bfc   = (const float*)d_in[15];
  float* out = (float*)d_out;
  float* W = (float*)d_ws;
  unsigned long long* argbest = (unsigned long long*)(W + FO_ARG);
  unsigned long long* s1buf   = (unsigned long long*)(W + FO_S1);
  float* cwT   = W + FO_CWT;
  float* Qp    = W + FO_QP;
  float* wbuf  = W + FO_W;
  float2* msbuf = (float2*)(W + FO_MS);
  float* ypart = W + FO_YP;
  float* ybuf  = W + FO_Y;
  float* O1    = W + FO_O1;
  float* O2    = W + FO_O2;

  hipLaunchKernelGGL(k_init,    dim3(36),   dim3(256), 0, stream, convw, cwT);
  hipLaunchKernelGGL(k_argmax1, dim3(2048), dim3(256), 0, stream, inp, Wenc, benc, s1buf);
  hipLaunchKernelGGL(k_argmax2, dim3(8),    dim3(256), 0, stream, s1buf, argbest);
  hipLaunchKernelGGL(k_qp,      dim3(2048), dim3(256), 0, stream, inp, Wq, bq, argbest, Qp);
  hipLaunchKernelGGL(k_w,       dim3(256),  dim3(256), 0, stream, Wk, Qp, wbuf);
  hipLaunchKernelGGL(k_fused,   dim3(512),  dim3(512), 0, stream, inp, convb, cwT, wbuf, argbest, msbuf, ypart);
  hipLaunchKernelGGL(k_comb,    dim3(512),  dim3(256), 0, stream, msbuf, wbuf, cls, ypart, ybuf);
  hipLaunchKernelGGL(k_o1,      dim3(2048), dim3(256), 0, stream, Wv, bv, Qp, ybuf, O1);
  hipLaunchKernelGGL(k_o2,      dim3(2048), dim3(256), 0, stream, Wo, bo, O1, O2);
  hipLaunchKernelGGL(k_out,     dim3(1),    dim3(256), 0, stream, Wfc, bfc, O2, out);
}